// Round 11
// baseline (869.556 us; speedup 1.0000x reference)
//
#include <hip/hip_runtime.h>
#include <cstdint>

#define NN 100000
#define NE 1600000
#define HD 128
#define NL 4
#define NC 12
#define NG 512
#define NB ((NN + 255) / 256)   // 391
#define NSH 8
#define SHN (NN / NSH)          // 12500
#define BCAP 204800             // per-bucket bin capacity (avg 200k, +11 sigma)
#define CHKB 4096               // entries per block-chunk in degB/fillB
#define BIN_BLOCKS 625          // 625 * 2560 = NE
#define BIN_ITERS 5             // 5 * 512 = 2560 edges per block
#define STCAP 2000              // LDS stage entries per bucket (8*2000*4B = 64000B)
#define BN_EPS 1e-5f

typedef _Float16 f16;
typedef _Float16 f16x2 __attribute__((ext_vector_type(2)));
typedef _Float16 f16x8 __attribute__((ext_vector_type(8)));
typedef float f32x4 __attribute__((ext_vector_type(4)));

__device__ __forceinline__ int get_xcc() {
    unsigned x;
    asm volatile("s_getreg_b32 %0, hwreg(HW_REG_XCC_ID)" : "=s"(x));
    return (int)(x & 7u);
}

// ---- pass 1: bin edges by dst range, packed (dlocal<<17 | s), dense writes
__global__ __launch_bounds__(256) void binP_kernel(const int* __restrict__ ei,
                                                   unsigned* __restrict__ gcur,
                                                   unsigned* __restrict__ bins) {
    __shared__ unsigned stage[NSH][STCAP];
    __shared__ unsigned cnt[NSH], fcnt[NSH], fbase[NSH];
    const int t = threadIdx.x;
    if (t < NSH) cnt[t] = 0;
    __syncthreads();
    const int e0base = blockIdx.x * (BIN_ITERS * 512);
    for (int it = 0; it < BIN_ITERS; ++it) {
        // push 512 edges (2 per thread)
#pragma unroll
        for (int r = 0; r < 2; ++r) {
            int e = e0base + it * 512 + r * 256 + t;
            unsigned s = (unsigned)ei[e];
            unsigned d = (unsigned)ei[NE + e];
            unsigned b = d / SHN;
            unsigned packed = ((d - b * SHN) << 17) | s;
            unsigned p = atomicAdd(&cnt[b], 1u);
            stage[b][p] = packed;
        }
        __syncthreads();
        bool last = (it == BIN_ITERS - 1);
        if (t < NSH) {
            unsigned c = cnt[t];
            bool fl = last ? (c > 0) : (c >= (STCAP - 512));
            fcnt[t] = fl ? c : 0;
            if (fl) fbase[t] = atomicAdd(&gcur[t], c);
        }
        __syncthreads();
#pragma unroll
        for (int b = 0; b < NSH; ++b) {
            unsigned c = fcnt[b];
            if (c == 0) continue;
            unsigned base = fbase[b];
            for (unsigned i = t; i < c; i += 256)
                bins[(size_t)b * BCAP + base + i] = stage[b][i];
        }
        __syncthreads();
        if (t < NSH && fcnt[t]) cnt[t] = 0;
        __syncthreads();
    }
}

// ---- pass 2a: XCD-pinned degree histogram over own bucket ----
__global__ __launch_bounds__(256) void degB_kernel(const unsigned* __restrict__ bins,
                                                   const unsigned* __restrict__ bcnt,
                                                   unsigned* __restrict__ ctr,
                                                   unsigned* __restrict__ deg) {
    __shared__ unsigned sbase;
    const int t = threadIdx.x;
    const int xcd = get_xcc();
    for (int bb = 0; bb < NSH; ++bb) {
        int b = (xcd + bb) & (NSH - 1);
        unsigned n = bcnt[b];
        if (bb > 0 && ((const volatile unsigned*)ctr)[b] * CHKB >= n) continue;
        for (;;) {
            if (t == 0) sbase = atomicAdd(&ctr[b], 1u) * CHKB;
            __syncthreads();
            unsigned base = sbase;
            if (base >= n) break;
            unsigned end = min(base + CHKB, n);
            for (unsigned i = base + t; i < end; i += 256) {
                unsigned p = bins[(size_t)b * BCAP + i];
                atomicAdd(&deg[(p >> 17) + (unsigned)b * SHN], 1u);
            }
            __syncthreads();
        }
    }
}

__global__ __launch_bounds__(256) void dinv_kernel(const unsigned* __restrict__ deg,
                                                   float* __restrict__ dinv) {
    int i = blockIdx.x * 256 + threadIdx.x;
    if (i < NN) dinv[i] = rsqrtf((float)deg[i] + 1.0f);
}

// ---- parallel scan ----
__global__ __launch_bounds__(256) void scanA_kernel(const unsigned* __restrict__ deg,
                                                    int* __restrict__ loc,
                                                    int* __restrict__ bsum) {
    __shared__ int sh[256];
    int t = threadIdx.x;
    int i = blockIdx.x * 256 + t;
    int v = (i < NN) ? (int)deg[i] : 0;
    sh[t] = v;
    __syncthreads();
    for (int off = 1; off < 256; off <<= 1) {
        int x = sh[t];
        int add = (t >= off) ? sh[t - off] : 0;
        __syncthreads();
        sh[t] = x + add;
        __syncthreads();
    }
    if (i < NN) loc[i] = sh[t] - v;
    if (t == 255) bsum[blockIdx.x] = sh[255];
}

__global__ __launch_bounds__(512) void scanB_kernel(int* __restrict__ bsum) {
    __shared__ int sh[512];
    int t = threadIdx.x;
    int v = (t < NB) ? bsum[t] : 0;
    sh[t] = v;
    __syncthreads();
    for (int off = 1; off < 512; off <<= 1) {
        int x = sh[t];
        int add = (t >= off) ? sh[t - off] : 0;
        __syncthreads();
        sh[t] = x + add;
        __syncthreads();
    }
    if (t < NB) bsum[t] = sh[t] - v;
}

__global__ __launch_bounds__(256) void scanC_kernel(const int* __restrict__ loc,
                                                    const int* __restrict__ bsum,
                                                    int* __restrict__ offsets,
                                                    unsigned* __restrict__ cursor) {
    int i = blockIdx.x * 256 + threadIdx.x;
    if (i < NN) {
        int o = bsum[blockIdx.x] + loc[i];
        offsets[i] = o;
        cursor[i] = (unsigned)o;
    }
    if (i == 0) offsets[NN] = NE;
}

// ---- pass 2b: XCD-pinned CSR fill (stores land in own XCD's L2 slab) ----
__global__ __launch_bounds__(256) void fillB_kernel(const unsigned* __restrict__ bins,
                                                    const unsigned* __restrict__ bcnt,
                                                    unsigned* __restrict__ ctr,
                                                    const float* __restrict__ dinv,
                                                    unsigned* __restrict__ cursor,
                                                    float2* __restrict__ csr) {
    __shared__ unsigned sbase;
    const int t = threadIdx.x;
    const int xcd = get_xcc();
    for (int bb = 0; bb < NSH; ++bb) {
        int b = (xcd + bb) & (NSH - 1);
        unsigned n = bcnt[b];
        if (bb > 0 && ((const volatile unsigned*)ctr)[b] * CHKB >= n) continue;
        for (;;) {
            if (t == 0) sbase = atomicAdd(&ctr[b], 1u) * CHKB;
            __syncthreads();
            unsigned base = sbase;
            if (base >= n) break;
            unsigned end = min(base + CHKB, n);
            for (unsigned i = base + t; i < end; i += 256) {
                unsigned p = bins[(size_t)b * BCAP + i];
                unsigned s = p & 0x1FFFFu;
                unsigned d = (p >> 17) + (unsigned)b * SHN;
                float coef = dinv[s] * dinv[d];
                unsigned pos = atomicAdd(&cursor[d], 1u);
                csr[pos] = make_float2(__int_as_float((int)s), coef);
            }
            __syncthreads();
        }
    }
}

// per-layer BN fold: val = acc*A + B
__global__ __launch_bounds__(128) void bnpre_kernel(const float* __restrict__ cb,
                                                    const float* __restrict__ gam,
                                                    const float* __restrict__ bet,
                                                    const float* __restrict__ mu,
                                                    const float* __restrict__ var,
                                                    float* __restrict__ bnA,
                                                    float* __restrict__ bnB) {
    int i = blockIdx.x * 128 + threadIdx.x;
    float a = gam[i] * rsqrtf(var[i] + BN_EPS);
    bnA[i] = a;
    bnB[i] = (cb[i] - mu[i]) * a + bet[i];
}

// graph boundaries
__global__ __launch_bounds__(64) void gboff_kernel(const int* __restrict__ batch,
                                                   int* __restrict__ goff) {
    int g = blockIdx.x * 64 + threadIdx.x;
    if (g > NG) return;
    int lo = 0, hi = NN;
    while (lo < hi) {
        int mid = (lo + hi) >> 1;
        if (batch[mid] < g) lo = mid + 1; else hi = mid;
    }
    goff[g] = lo;
}

// weights: fp32 [k][n] -> fp16 transposed [n][k] (5 matrices)
__global__ __launch_bounds__(128) void wconv_kernel(const float* __restrict__ w_in,
                                                    const float* __restrict__ conv_w,
                                                    f16* __restrict__ Wt) {
    int m = blockIdx.x >> 7;       // 0..4
    int k = blockIdx.x & 127;
    int n = threadIdx.x;
    const float* src = (m == 0) ? w_in : conv_w + (size_t)(m - 1) * HD * HD;
    Wt[((size_t)m * HD + n) * HD + k] = (f16)src[k * HD + n];
}

// ---------------- MFMA GEMM: [NN,128] x Wt[n][k](f16) -> f16 -------------
// MODE 0: A is fp32, out = relu(acc + bias)   MODE 1: A is fp16, out = acc
template <int MODE>
__global__ __launch_bounds__(256) void gemm_mfma(const void* __restrict__ Av,
                                                 const f16* __restrict__ Wt,
                                                 const float* __restrict__ bias,
                                                 f16* __restrict__ out) {
    const int l = threadIdx.x & 63;
    const int w = threadIdx.x >> 6;
    const int row0 = blockIdx.x * 64 + w * 16;
    const int l15 = l & 15;
    const int kg = (l >> 4) * 8;
    int ar = row0 + l15;
    if (ar >= NN) ar = NN - 1;
    const f16* Wb = Wt + (size_t)l15 * HD + kg;
    f32x4 acc[8];
    const f32x4 z = {0.f, 0.f, 0.f, 0.f};
#pragma unroll
    for (int t = 0; t < 8; ++t) acc[t] = z;
#pragma unroll
    for (int ks = 0; ks < 4; ++ks) {
        f16x8 a;
        if (MODE == 0) {
            const float* Arow = (const float*)Av + (size_t)ar * HD + kg;
            float4 v0 = *(const float4*)(Arow + ks * 32);
            float4 v1 = *(const float4*)(Arow + ks * 32 + 4);
            a = (f16x8){(f16)v0.x, (f16)v0.y, (f16)v0.z, (f16)v0.w,
                        (f16)v1.x, (f16)v1.y, (f16)v1.z, (f16)v1.w};
        } else {
            const f16* Arow = (const f16*)Av + (size_t)ar * HD + kg;
            a = *(const f16x8*)(Arow + ks * 32);
        }
#pragma unroll
        for (int t = 0; t < 8; ++t) {
            f16x8 b = *(const f16x8*)(Wb + (size_t)t * 16 * HD + ks * 32);
            acc[t] = __builtin_amdgcn_mfma_f32_16x16x32_f16(a, b, acc[t], 0, 0, 0);
        }
    }
    const int orow = row0 + (l >> 4) * 4;
#pragma unroll
    for (int r = 0; r < 4; ++r) {
        int gr = orow + r;
        if (gr < NN) {
            f16* op = out + (size_t)gr * HD + l15;
#pragma unroll
            for (int t = 0; t < 8; ++t) {
                float v = acc[t][r];
                if (MODE == 0) v = fmaxf(v + bias[t * 16 + l15], 0.f);
                op[t * 16] = (f16)v;
            }
        }
    }
}

// ------- pull aggregation + BN + ReLU (one wave/node, 8 gathers in flight) --
__global__ __launch_bounds__(256) void agg_kernel(const int* __restrict__ offsets,
                                                  const float2* __restrict__ csr,
                                                  const float* __restrict__ dinv,
                                                  const f16x2* __restrict__ hw2,
                                                  const float* __restrict__ bnA,
                                                  const float* __restrict__ bnB,
                                                  f16x2* __restrict__ hout) {
    int w = (blockIdx.x * 256 + threadIdx.x) >> 6;
    int lane = threadIdx.x & 63;
    if (w >= NN) return;
    int c = lane * 2;
    int b0 = offsets[w];
    int b1 = offsets[w + 1];
    float di = dinv[w];
    f16x2 v = hw2[(size_t)w * 64 + lane];
    float ax = di * di * (float)v.x, ay = di * di * (float)v.y;
    int j = b0;
    for (; j + 8 <= b1; j += 8) {
        float2 e0 = csr[j + 0], e1 = csr[j + 1], e2 = csr[j + 2], e3 = csr[j + 3];
        float2 e4 = csr[j + 4], e5 = csr[j + 5], e6 = csr[j + 6], e7 = csr[j + 7];
        f16x2 u0 = hw2[(size_t)__float_as_int(e0.x) * 64 + lane];
        f16x2 u1 = hw2[(size_t)__float_as_int(e1.x) * 64 + lane];
        f16x2 u2 = hw2[(size_t)__float_as_int(e2.x) * 64 + lane];
        f16x2 u3 = hw2[(size_t)__float_as_int(e3.x) * 64 + lane];
        f16x2 u4 = hw2[(size_t)__float_as_int(e4.x) * 64 + lane];
        f16x2 u5 = hw2[(size_t)__float_as_int(e5.x) * 64 + lane];
        f16x2 u6 = hw2[(size_t)__float_as_int(e6.x) * 64 + lane];
        f16x2 u7 = hw2[(size_t)__float_as_int(e7.x) * 64 + lane];
        ax = fmaf(e0.y, (float)u0.x, ax); ay = fmaf(e0.y, (float)u0.y, ay);
        ax = fmaf(e1.y, (float)u1.x, ax); ay = fmaf(e1.y, (float)u1.y, ay);
        ax = fmaf(e2.y, (float)u2.x, ax); ay = fmaf(e2.y, (float)u2.y, ay);
        ax = fmaf(e3.y, (float)u3.x, ax); ay = fmaf(e3.y, (float)u3.y, ay);
        ax = fmaf(e4.y, (float)u4.x, ax); ay = fmaf(e4.y, (float)u4.y, ay);
        ax = fmaf(e5.y, (float)u5.x, ax); ay = fmaf(e5.y, (float)u5.y, ay);
        ax = fmaf(e6.y, (float)u6.x, ax); ay = fmaf(e6.y, (float)u6.y, ay);
        ax = fmaf(e7.y, (float)u7.x, ax); ay = fmaf(e7.y, (float)u7.y, ay);
    }
    for (; j < b1; ++j) {
        float2 e = csr[j];
        f16x2 u = hw2[(size_t)__float_as_int(e.x) * 64 + lane];
        ax = fmaf(e.y, (float)u.x, ax);
        ay = fmaf(e.y, (float)u.y, ay);
    }
    float rx = fmaxf(fmaf(ax, bnA[c], bnB[c]), 0.f);
    float ry = fmaxf(fmaf(ay, bnA[c + 1], bnB[c + 1]), 0.f);
    f16x2 o = {(f16)rx, (f16)ry};
    hout[(size_t)w * 64 + lane] = o;
}

// ---------------- segmented mean pool (fp16 input) ----------------
__global__ __launch_bounds__(256) void pool_kernel(const f16x2* __restrict__ h2,
                                                   const int* __restrict__ goff,
                                                   float* __restrict__ g) {
    int b = blockIdx.x, t = threadIdx.x;
    int p = t & 63, q = t >> 6;
    int i0 = goff[b], i1 = goff[b + 1];
    float sx = 0.f, sy = 0.f;
    for (int i = i0 + q; i < i1; i += 4) {
        f16x2 v = h2[(size_t)i * 64 + p];
        sx += (float)v.x;
        sy += (float)v.y;
    }
    __shared__ float shx[4][64], shy[4][64];
    shx[q][p] = sx;
    shy[q][p] = sy;
    __syncthreads();
    if (q == 0) {
        float fx = shx[0][p] + shx[1][p] + shx[2][p] + shx[3][p];
        float fy = shy[0][p] + shy[1][p] + shy[2][p] + shy[3][p];
        float invc = 1.0f / fmaxf((float)(i1 - i0), 1.0f);
        *(float2*)&g[(size_t)b * HD + p * 2] = make_float2(fx * invc, fy * invc);
    }
}

// ---------------- per-graph MLP head ----------------
__global__ __launch_bounds__(64) void mlp_kernel(const float* __restrict__ g,
                                                 const float* __restrict__ fc1w,
                                                 const float* __restrict__ fc1b,
                                                 const float* __restrict__ fc2w,
                                                 const float* __restrict__ fc2b,
                                                 float* __restrict__ out) {
    __shared__ float gr[128];
    __shared__ float f1[64];
    int b = blockIdx.x, t = threadIdx.x;
    gr[t] = g[(size_t)b * HD + t];
    gr[t + 64] = g[(size_t)b * HD + 64 + t];
    __syncthreads();
    float acc = fc1b[t];
#pragma unroll 8
    for (int k = 0; k < 128; ++k) acc = fmaf(gr[k], fc1w[k * 64 + t], acc);
    f1[t] = fmaxf(acc, 0.f);
    __syncthreads();
    if (t < NC) {
        float a2 = fc2b[t];
#pragma unroll 8
        for (int k = 0; k < 64; ++k) a2 = fmaf(f1[k], fc2w[k * NC + t], a2);
        out[b * NC + t] = a2;
    }
    if (b == 0 && t == 63) out[NG * NC] = 0.0f;  // aux scalar output
}

// ---------------- launch ----------------
extern "C" void kernel_launch(void* const* d_in, const int* in_sizes, int n_in,
                              void* d_out, int out_size, void* d_ws, size_t ws_size,
                              hipStream_t stream) {
    const float* x      = (const float*)d_in[0];
    const int*   ei     = (const int*)d_in[1];
    const int*   batch  = (const int*)d_in[2];
    const float* w_in   = (const float*)d_in[3];
    const float* b_in   = (const float*)d_in[4];
    const float* conv_w = (const float*)d_in[5];
    const float* conv_b = (const float*)d_in[6];
    const float* gam    = (const float*)d_in[7];
    const float* bet    = (const float*)d_in[8];
    const float* mu     = (const float*)d_in[9];
    const float* var    = (const float*)d_in[10];
    const float* fc1w   = (const float*)d_in[11];
    const float* fc1b   = (const float*)d_in[12];
    const float* fc2w   = (const float*)d_in[13];
    const float* fc2b   = (const float*)d_in[14];
    float* out = (float*)d_out;

    char* p = (char*)d_ws;
    auto alloc = [&](size_t bytes) -> void* {
        void* r = (void*)p;
        p += (bytes + 255) & ~(size_t)255;
        return r;
    };
    size_t NH = (size_t)NN * HD;
    f16* h        = (f16*)alloc(NH * 2);
    f16* hw       = (f16*)alloc(NH * 2);
    f16* Wt       = (f16*)alloc((size_t)5 * HD * HD * 2);
    float2* csr   = (float2*)alloc((size_t)NE * 8);
    unsigned* bins = (unsigned*)alloc((size_t)NSH * BCAP * 4);
    unsigned* deg = (unsigned*)alloc(NN * 4);
    unsigned* ctrs = (unsigned*)alloc(768);   // gcur(8) | ctrD(8) | ctrF(8)
    float* dinv   = (float*)alloc(NN * 4);
    float* bnA    = (float*)alloc(NL * HD * 4);
    float* bnB    = (float*)alloc(NL * HD * 4);
    float* g      = (float*)alloc(NG * HD * 4);
    int* offsets  = (int*)alloc((NN + 1) * 4);
    unsigned* cursor = (unsigned*)alloc(NN * 4);
    int* loc      = (int*)alloc(NN * 4);
    int* bsum     = (int*)alloc(NB * 4);
    int* goff     = (int*)alloc((NG + 1) * 4);
    unsigned* gcur = ctrs;
    unsigned* ctrD = ctrs + 64;
    unsigned* ctrF = ctrs + 128;

    hipMemsetAsync(deg, 0, NN * 4, stream);
    hipMemsetAsync(ctrs, 0, 768, stream);

    binP_kernel<<<BIN_BLOCKS, 256, 0, stream>>>(ei, gcur, bins);
    degB_kernel<<<1024, 256, 0, stream>>>(bins, gcur, ctrD, deg);
    dinv_kernel<<<NB, 256, 0, stream>>>(deg, dinv);
    scanA_kernel<<<NB, 256, 0, stream>>>(deg, loc, bsum);
    scanB_kernel<<<1, 512, 0, stream>>>(bsum);
    scanC_kernel<<<NB, 256, 0, stream>>>(loc, bsum, offsets, cursor);
    fillB_kernel<<<1024, 256, 0, stream>>>(bins, gcur, ctrF, dinv, cursor, csr);
    bnpre_kernel<<<NL, 128, 0, stream>>>(conv_b, gam, bet, mu, var, bnA, bnB);
    gboff_kernel<<<(NG + 64) / 64, 64, 0, stream>>>(batch, goff);
    wconv_kernel<<<5 * 128, 128, 0, stream>>>(w_in, conv_w, Wt);

    int gblocks = (NN + 63) / 64;
    gemm_mfma<0><<<gblocks, 256, 0, stream>>>(x, Wt, b_in, h);

    for (int l = 0; l < NL; ++l) {
        gemm_mfma<1><<<gblocks, 256, 0, stream>>>(h, Wt + (size_t)(l + 1) * HD * HD,
                                                  nullptr, hw);
        agg_kernel<<<(NN * 64 + 255) / 256, 256, 0, stream>>>(
            offsets, csr, dinv, (const f16x2*)hw, bnA + l * HD, bnB + l * HD,
            (f16x2*)h);
    }

    pool_kernel<<<NG, 256, 0, stream>>>((const f16x2*)h, goff, g);
    mlp_kernel<<<NG, 64, 0, stream>>>(g, fc1w, fc1b, fc2w, fc2b, out);
}

// Round 12
// 758.013 us; speedup vs baseline: 1.1472x; 1.1472x over previous
//
#include <hip/hip_runtime.h>
#include <cstdint>

#define NN 100000
#define NE 1600000
#define HD 128
#define NL 4
#define NC 12
#define NG 512
#define NB ((NN + 255) / 256)   // 391
#define NEB (NE / 256)          // 6250
#define NSH 8
#define BN_EPS 1e-5f

typedef _Float16 f16;
typedef _Float16 f16x2 __attribute__((ext_vector_type(2)));
typedef _Float16 f16x8 __attribute__((ext_vector_type(8)));
typedef float f32x4 __attribute__((ext_vector_type(4)));

// ---------------- sharded degree histogram (1 edge/thread) ----------------
__global__ __launch_bounds__(256) void degS_kernel(const int* __restrict__ ei,
                                                   unsigned* __restrict__ degS) {
    int e = blockIdx.x * 256 + threadIdx.x;
    int sh = blockIdx.x & (NSH - 1);
    atomicAdd(&degS[(size_t)sh * NN + ei[NE + e]], 1u);
}

__global__ __launch_bounds__(256) void degsum_kernel(const unsigned* __restrict__ degS,
                                                     int* __restrict__ deg) {
    int i = blockIdx.x * 256 + threadIdx.x;
    if (i < NN) {
        unsigned s = 0;
#pragma unroll
        for (int sh = 0; sh < NSH; ++sh) s += degS[(size_t)sh * NN + i];
        deg[i] = (int)s;
    }
}

__global__ __launch_bounds__(256) void dinv_kernel(const int* __restrict__ deg,
                                                   float* __restrict__ dinv) {
    int i = blockIdx.x * 256 + threadIdx.x;
    if (i < NN) dinv[i] = rsqrtf((float)deg[i] + 1.0f);
}

// ---- parallel scan ----
__global__ __launch_bounds__(256) void scanA_kernel(const int* __restrict__ deg,
                                                    int* __restrict__ loc,
                                                    int* __restrict__ bsum) {
    __shared__ int sh[256];
    int t = threadIdx.x;
    int i = blockIdx.x * 256 + t;
    int v = (i < NN) ? deg[i] : 0;
    sh[t] = v;
    __syncthreads();
    for (int off = 1; off < 256; off <<= 1) {
        int x = sh[t];
        int add = (t >= off) ? sh[t - off] : 0;
        __syncthreads();
        sh[t] = x + add;
        __syncthreads();
    }
    if (i < NN) loc[i] = sh[t] - v;
    if (t == 255) bsum[blockIdx.x] = sh[255];
}

__global__ __launch_bounds__(512) void scanB_kernel(int* __restrict__ bsum) {
    __shared__ int sh[512];
    int t = threadIdx.x;
    int v = (t < NB) ? bsum[t] : 0;
    sh[t] = v;
    __syncthreads();
    for (int off = 1; off < 512; off <<= 1) {
        int x = sh[t];
        int add = (t >= off) ? sh[t - off] : 0;
        __syncthreads();
        sh[t] = x + add;
        __syncthreads();
    }
    if (t < NB) bsum[t] = sh[t] - v;
}

__global__ __launch_bounds__(256) void scanC_kernel(const int* __restrict__ loc,
                                                    const int* __restrict__ bsum,
                                                    int* __restrict__ offsets) {
    int i = blockIdx.x * 256 + threadIdx.x;
    if (i < NN) offsets[i] = bsum[blockIdx.x] + loc[i];
    if (i == 0) offsets[NN] = NE;
}

// per-node per-shard cursor init
__global__ __launch_bounds__(256) void cursorS_kernel(const int* __restrict__ offsets,
                                                      const unsigned* __restrict__ degS,
                                                      unsigned* __restrict__ cursorS) {
    int i = blockIdx.x * 256 + threadIdx.x;
    if (i < NN) {
        int base = offsets[i];
#pragma unroll
        for (int sh = 0; sh < NSH; ++sh) {
            cursorS[(size_t)sh * NN + i] = (unsigned)base;
            base += (int)degS[(size_t)sh * NN + i];
        }
    }
}

// fill CSR packed (src,coef) 8B; 1 edge/thread (measured-best config)
__global__ __launch_bounds__(256) void fillS_kernel(const int* __restrict__ ei,
                                                    const float* __restrict__ dinv,
                                                    unsigned* __restrict__ cursorS,
                                                    float2* __restrict__ csr) {
    int e = blockIdx.x * 256 + threadIdx.x;
    int sh = blockIdx.x & (NSH - 1);
    int s = ei[e];
    int d = ei[NE + e];
    unsigned pos = atomicAdd(&cursorS[(size_t)sh * NN + d], 1u);
    csr[pos] = make_float2(__int_as_float(s), dinv[s] * dinv[d]);
}

// per-layer BN fold: val = acc*A + B
__global__ __launch_bounds__(128) void bnpre_kernel(const float* __restrict__ cb,
                                                    const float* __restrict__ gam,
                                                    const float* __restrict__ bet,
                                                    const float* __restrict__ mu,
                                                    const float* __restrict__ var,
                                                    float* __restrict__ bnA,
                                                    float* __restrict__ bnB) {
    int i = blockIdx.x * 128 + threadIdx.x;
    float a = gam[i] * rsqrtf(var[i] + BN_EPS);
    bnA[i] = a;
    bnB[i] = (cb[i] - mu[i]) * a + bet[i];
}

// graph boundaries
__global__ __launch_bounds__(64) void gboff_kernel(const int* __restrict__ batch,
                                                   int* __restrict__ goff) {
    int g = blockIdx.x * 64 + threadIdx.x;
    if (g > NG) return;
    int lo = 0, hi = NN;
    while (lo < hi) {
        int mid = (lo + hi) >> 1;
        if (batch[mid] < g) lo = mid + 1; else hi = mid;
    }
    goff[g] = lo;
}

// weights: fp32 [k][n] -> fp16 transposed [n][k] (5 matrices)
__global__ __launch_bounds__(128) void wconv_kernel(const float* __restrict__ w_in,
                                                    const float* __restrict__ conv_w,
                                                    f16* __restrict__ Wt) {
    int m = blockIdx.x >> 7;       // 0..4
    int k = blockIdx.x & 127;
    int n = threadIdx.x;
    const float* src = (m == 0) ? w_in : conv_w + (size_t)(m - 1) * HD * HD;
    Wt[((size_t)m * HD + n) * HD + k] = (f16)src[k * HD + n];
}

// ---------------- MFMA GEMM (input projection only): fp32 A -> f16 out ----
__global__ __launch_bounds__(256) void gemm_mfma(const float* __restrict__ A,
                                                 const f16* __restrict__ Wt,
                                                 const float* __restrict__ bias,
                                                 f16* __restrict__ out) {
    const int l = threadIdx.x & 63;
    const int w = threadIdx.x >> 6;
    const int row0 = blockIdx.x * 64 + w * 16;
    const int l15 = l & 15;
    const int kg = (l >> 4) * 8;
    int ar = row0 + l15;
    if (ar >= NN) ar = NN - 1;
    const f16* Wb = Wt + (size_t)l15 * HD + kg;
    f32x4 acc[8];
    const f32x4 z = {0.f, 0.f, 0.f, 0.f};
#pragma unroll
    for (int t = 0; t < 8; ++t) acc[t] = z;
#pragma unroll
    for (int ks = 0; ks < 4; ++ks) {
        const float* Arow = A + (size_t)ar * HD + kg;
        float4 v0 = *(const float4*)(Arow + ks * 32);
        float4 v1 = *(const float4*)(Arow + ks * 32 + 4);
        f16x8 a = {(f16)v0.x, (f16)v0.y, (f16)v0.z, (f16)v0.w,
                   (f16)v1.x, (f16)v1.y, (f16)v1.z, (f16)v1.w};
#pragma unroll
        for (int t = 0; t < 8; ++t) {
            f16x8 b = *(const f16x8*)(Wb + (size_t)t * 16 * HD + ks * 32);
            acc[t] = __builtin_amdgcn_mfma_f32_16x16x32_f16(a, b, acc[t], 0, 0, 0);
        }
    }
    const int orow = row0 + (l >> 4) * 4;
#pragma unroll
    for (int r = 0; r < 4; ++r) {
        int gr = orow + r;
        if (gr < NN) {
            f16* op = out + (size_t)gr * HD + l15;
#pragma unroll
            for (int t = 0; t < 8; ++t) {
                float v = fmaxf(acc[t][r] + bias[t * 16 + l15], 0.f);
                op[t * 16] = (f16)v;
            }
        }
    }
}

// ---- fused layer: z = A_hat @ h (gather) then hout = relu(BN(z @ W)) ----
// block = 16 nodes (NN = 6250*16 exact), 4 waves.
__global__ __launch_bounds__(256) void layer_kernel(const int* __restrict__ offsets,
                                                    const float2* __restrict__ csr,
                                                    const float* __restrict__ dinv,
                                                    const f16* __restrict__ hin,
                                                    const f16* __restrict__ Wt,
                                                    const float* __restrict__ bnA,
                                                    const float* __restrict__ bnB,
                                                    f16* __restrict__ hout) {
    __shared__ unsigned aU[16 * 64];  // [16 rows][64 u32], XOR-swizzled
    const int t = threadIdx.x;
    const int w = t >> 6, lane = t & 63;
    const int n0 = blockIdx.x * 16;
    const f16x2* h2 = (const f16x2*)hin;

    // phase 1: each wave gathers 4 node rows (z = A_hat @ h), 8 loads in flight
    for (int r = 0; r < 4; ++r) {
        int node = n0 + w * 4 + r;
        int b0 = offsets[node];
        int b1 = offsets[node + 1];
        float di = dinv[node];
        f16x2 v = h2[(size_t)node * 64 + lane];
        float ax = di * di * (float)v.x, ay = di * di * (float)v.y;
        int j = b0;
        for (; j + 8 <= b1; j += 8) {
            float2 e0 = csr[j + 0], e1 = csr[j + 1], e2 = csr[j + 2], e3 = csr[j + 3];
            float2 e4 = csr[j + 4], e5 = csr[j + 5], e6 = csr[j + 6], e7 = csr[j + 7];
            f16x2 u0 = h2[(size_t)__float_as_int(e0.x) * 64 + lane];
            f16x2 u1 = h2[(size_t)__float_as_int(e1.x) * 64 + lane];
            f16x2 u2 = h2[(size_t)__float_as_int(e2.x) * 64 + lane];
            f16x2 u3 = h2[(size_t)__float_as_int(e3.x) * 64 + lane];
            f16x2 u4 = h2[(size_t)__float_as_int(e4.x) * 64 + lane];
            f16x2 u5 = h2[(size_t)__float_as_int(e5.x) * 64 + lane];
            f16x2 u6 = h2[(size_t)__float_as_int(e6.x) * 64 + lane];
            f16x2 u7 = h2[(size_t)__float_as_int(e7.x) * 64 + lane];
            ax = fmaf(e0.y, (float)u0.x, ax); ay = fmaf(e0.y, (float)u0.y, ay);
            ax = fmaf(e1.y, (float)u1.x, ax); ay = fmaf(e1.y, (float)u1.y, ay);
            ax = fmaf(e2.y, (float)u2.x, ax); ay = fmaf(e2.y, (float)u2.y, ay);
            ax = fmaf(e3.y, (float)u3.x, ax); ay = fmaf(e3.y, (float)u3.y, ay);
            ax = fmaf(e4.y, (float)u4.x, ax); ay = fmaf(e4.y, (float)u4.y, ay);
            ax = fmaf(e5.y, (float)u5.x, ax); ay = fmaf(e5.y, (float)u5.y, ay);
            ax = fmaf(e6.y, (float)u6.x, ax); ay = fmaf(e6.y, (float)u6.y, ay);
            ax = fmaf(e7.y, (float)u7.x, ax); ay = fmaf(e7.y, (float)u7.y, ay);
        }
        for (; j < b1; ++j) {
            float2 e = csr[j];
            f16x2 u = h2[(size_t)__float_as_int(e.x) * 64 + lane];
            ax = fmaf(e.y, (float)u.x, ax);
            ay = fmaf(e.y, (float)u.y, ay);
        }
        f16x2 o = {(f16)ax, (f16)ay};
        int row = w * 4 + r;
        aU[(row * 64 + lane) ^ ((row & 7) << 2)] = *(const unsigned*)&o;
    }
    __syncthreads();

    // phase 2: [16,128] @ Wt[n][k] -> each wave 2 col-tiles (8 MFMA)
    const int l15 = lane & 15, hi = lane >> 4;
    const f32x4 z = {0.f, 0.f, 0.f, 0.f};
    f32x4 acc0 = z, acc1 = z;
    const int ct0 = w * 2, ct1 = w * 2 + 1;
    const f16* Wb0 = Wt + (size_t)(ct0 * 16 + l15) * HD + hi * 8;
    const f16* Wb1 = Wt + (size_t)(ct1 * 16 + l15) * HD + hi * 8;
#pragma unroll
    for (int ks = 0; ks < 4; ++ks) {
        f16x8 a = *(const f16x8*)&aU[(l15 * 64 + ks * 16 + hi * 4) ^ ((l15 & 7) << 2)];
        f16x8 b0 = *(const f16x8*)(Wb0 + ks * 32);
        f16x8 b1 = *(const f16x8*)(Wb1 + ks * 32);
        acc0 = __builtin_amdgcn_mfma_f32_16x16x32_f16(a, b0, acc0, 0, 0, 0);
        acc1 = __builtin_amdgcn_mfma_f32_16x16x32_f16(a, b1, acc1, 0, 0, 0);
    }
    const int c0 = ct0 * 16 + l15, c1 = ct1 * 16 + l15;
    const float A0 = bnA[c0], B0 = bnB[c0];
    const float A1 = bnA[c1], B1 = bnB[c1];
#pragma unroll
    for (int r = 0; r < 4; ++r) {
        int node = n0 + hi * 4 + r;
        float v0 = fmaxf(fmaf(acc0[r], A0, B0), 0.f);
        float v1 = fmaxf(fmaf(acc1[r], A1, B1), 0.f);
        hout[(size_t)node * HD + c0] = (f16)v0;
        hout[(size_t)node * HD + c1] = (f16)v1;
    }
}

// ---------------- segmented mean pool (fp16 input) ----------------
__global__ __launch_bounds__(256) void pool_kernel(const f16x2* __restrict__ h2,
                                                   const int* __restrict__ goff,
                                                   float* __restrict__ g) {
    int b = blockIdx.x, t = threadIdx.x;
    int p = t & 63, q = t >> 6;
    int i0 = goff[b], i1 = goff[b + 1];
    float sx = 0.f, sy = 0.f;
    for (int i = i0 + q; i < i1; i += 4) {
        f16x2 v = h2[(size_t)i * 64 + p];
        sx += (float)v.x;
        sy += (float)v.y;
    }
    __shared__ float shx[4][64], shy[4][64];
    shx[q][p] = sx;
    shy[q][p] = sy;
    __syncthreads();
    if (q == 0) {
        float fx = shx[0][p] + shx[1][p] + shx[2][p] + shx[3][p];
        float fy = shy[0][p] + shy[1][p] + shy[2][p] + shy[3][p];
        float invc = 1.0f / fmaxf((float)(i1 - i0), 1.0f);
        *(float2*)&g[(size_t)b * HD + p * 2] = make_float2(fx * invc, fy * invc);
    }
}

// ---------------- per-graph MLP head ----------------
__global__ __launch_bounds__(64) void mlp_kernel(const float* __restrict__ g,
                                                 const float* __restrict__ fc1w,
                                                 const float* __restrict__ fc1b,
                                                 const float* __restrict__ fc2w,
                                                 const float* __restrict__ fc2b,
                                                 float* __restrict__ out) {
    __shared__ float gr[128];
    __shared__ float f1[64];
    int b = blockIdx.x, t = threadIdx.x;
    gr[t] = g[(size_t)b * HD + t];
    gr[t + 64] = g[(size_t)b * HD + 64 + t];
    __syncthreads();
    float acc = fc1b[t];
#pragma unroll 8
    for (int k = 0; k < 128; ++k) acc = fmaf(gr[k], fc1w[k * 64 + t], acc);
    f1[t] = fmaxf(acc, 0.f);
    __syncthreads();
    if (t < NC) {
        float a2 = fc2b[t];
#pragma unroll 8
        for (int k = 0; k < 64; ++k) a2 = fmaf(f1[k], fc2w[k * NC + t], a2);
        out[b * NC + t] = a2;
    }
    if (b == 0 && t == 63) out[NG * NC] = 0.0f;  // aux scalar output
}

// ---------------- launch ----------------
extern "C" void kernel_launch(void* const* d_in, const int* in_sizes, int n_in,
                              void* d_out, int out_size, void* d_ws, size_t ws_size,
                              hipStream_t stream) {
    const float* x      = (const float*)d_in[0];
    const int*   ei     = (const int*)d_in[1];
    const int*   batch  = (const int*)d_in[2];
    const float* w_in   = (const float*)d_in[3];
    const float* b_in   = (const float*)d_in[4];
    const float* conv_w = (const float*)d_in[5];
    const float* conv_b = (const float*)d_in[6];
    const float* gam    = (const float*)d_in[7];
    const float* bet    = (const float*)d_in[8];
    const float* mu     = (const float*)d_in[9];
    const float* var    = (const float*)d_in[10];
    const float* fc1w   = (const float*)d_in[11];
    const float* fc1b   = (const float*)d_in[12];
    const float* fc2w   = (const float*)d_in[13];
    const float* fc2b   = (const float*)d_in[14];
    float* out = (float*)d_out;

    char* p = (char*)d_ws;
    auto alloc = [&](size_t bytes) -> void* {
        void* r = (void*)p;
        p += (bytes + 255) & ~(size_t)255;
        return r;
    };
    size_t NH = (size_t)NN * HD;
    f16* hA       = (f16*)alloc(NH * 2);
    f16* hB       = (f16*)alloc(NH * 2);
    f16* Wt       = (f16*)alloc((size_t)5 * HD * HD * 2);
    float2* csr   = (float2*)alloc((size_t)NE * 8);
    int* deg      = (int*)alloc(NN * 4);
    float* dinv   = (float*)alloc(NN * 4);
    float* bnA    = (float*)alloc(NL * HD * 4);
    float* bnB    = (float*)alloc(NL * HD * 4);
    float* g      = (float*)alloc(NG * HD * 4);
    int* offsets  = (int*)alloc((NN + 1) * 4);
    int* loc      = (int*)alloc(NN * 4);
    int* bsum     = (int*)alloc(NB * 4);
    int* goff     = (int*)alloc((NG + 1) * 4);
    unsigned* degS    = (unsigned*)alloc((size_t)NSH * NN * 4);
    unsigned* cursorS = (unsigned*)alloc((size_t)NSH * NN * 4);

    hipMemsetAsync(degS, 0, (size_t)NSH * NN * 4, stream);

    degS_kernel<<<NEB, 256, 0, stream>>>(ei, degS);
    degsum_kernel<<<NB, 256, 0, stream>>>(degS, deg);
    dinv_kernel<<<NB, 256, 0, stream>>>(deg, dinv);
    scanA_kernel<<<NB, 256, 0, stream>>>(deg, loc, bsum);
    scanB_kernel<<<1, 512, 0, stream>>>(bsum);
    scanC_kernel<<<NB, 256, 0, stream>>>(loc, bsum, offsets);
    cursorS_kernel<<<NB, 256, 0, stream>>>(offsets, degS, cursorS);
    fillS_kernel<<<NEB, 256, 0, stream>>>(ei, dinv, cursorS, csr);
    bnpre_kernel<<<NL, 128, 0, stream>>>(conv_b, gam, bet, mu, var, bnA, bnB);
    gboff_kernel<<<(NG + 64) / 64, 64, 0, stream>>>(batch, goff);
    wconv_kernel<<<5 * 128, 128, 0, stream>>>(w_in, conv_w, Wt);

    gemm_mfma<<<(NN + 63) / 64, 256, 0, stream>>>(x, Wt, b_in, hA);

    f16* hin = hA;
    f16* hout = hB;
    for (int l = 0; l < NL; ++l) {
        layer_kernel<<<NN / 16, 256, 0, stream>>>(
            offsets, csr, dinv, hin, Wt + (size_t)(l + 1) * HD * HD,
            bnA + l * HD, bnB + l * HD, hout);
        f16* tmp = hin; hin = hout; hout = tmp;
    }

    pool_kernel<<<NG, 256, 0, stream>>>((const f16x2*)hin, goff, g);
    mlp_kernel<<<NG, 64, 0, stream>>>(g, fc1w, fc1b, fc2w, fc2b, out);
}